// Round 1
// baseline (2999.302 us; speedup 1.0000x reference)
//
#include <hip/hip_runtime.h>

// EGNN E_GCL fused kernels for MI355X (gfx950), bf16 MFMA path.
// N=50000 nodes, E=1600000 edges, F=H=128.
//
// Plan:
//  prep:  pack all weight matrices as bf16 MFMA A-fragments of W^T (wp),
//         convert h to bf16 row-major (hb).
//  edge:  per 64-edge tile: gather h[row],h[col] (bf16) into LDS in fragment
//         order; GEMM1 (+radial rank-1 fp32, +be1, SiLU) -> t1 frags in LDS;
//         GEMM2 (+be2, SiLU) -> edge_feat: f32 atomicAdd into agg_h (=d_out h
//         region) + frags to LDS; GEMM3 (+bc1, SiLU) dot Wc2 -> phi;
//         atomicAdd coord aggregates + count.
//  node:  per 64-node tile: [h | agg_h] @ Wn1 (+bn1, SiLU) @ Wn2 (+bn2),
//         residual add fp32 h, write h_out in place over agg_h.
//  coord: coord + agg_c / max(cnt,1).

typedef float f32x4 __attribute__((ext_vector_type(4)));
typedef short s16x8 __attribute__((ext_vector_type(8)));

#define NN  50000
#define EE  1600000
#define NHF 6400000   // N*128

__device__ __forceinline__ unsigned short f2bf(float x){
  union { float f; unsigned int u; } v; v.f = x;
  unsigned int r = v.u + 0x7fffu + ((v.u >> 16) & 1u);
  return (unsigned short)(r >> 16);
}
__device__ __forceinline__ unsigned int pack2(float a, float b){
  return (unsigned int)f2bf(a) | ((unsigned int)f2bf(b) << 16);
}
__device__ __forceinline__ float silu_f(float x){ return x / (1.f + __expf(-x)); }

__device__ __forceinline__ f32x4 mfma16(s16x8 a, s16x8 b, f32x4 c){
  return __builtin_amdgcn_mfma_f32_16x16x32_bf16(a, b, c, 0, 0, 0);
}

// ---------- weight pack: A-fragments of W^T ----------
// For mfma_f32_16x16x32_bf16, A-frag: lane holds A[row=lane&15][k=(lane>>4)*8+j].
// A = W^T so lane j holds W[ks*32+(lane>>4)*8+j][ft*16+(lane&15)].
// 7 matrices of [128][128]: 0=We1a 1=We1b 2=We2 3=Wc1 4=Wn1a 5=Wn1b 6=Wn2.
__global__ void pack_weights(const float* __restrict__ We1, const float* __restrict__ We2,
                             const float* __restrict__ Wc1, const float* __restrict__ Wn1,
                             const float* __restrict__ Wn2, short* __restrict__ wp)
{
  int b = blockIdx.x;              // 7*32 blocks, 64 threads
  int m = b >> 5, t = b & 31;
  int ft = t >> 2, ks = t & 3;
  int lane = threadIdx.x;
  const float* src;
  switch (m) {
    case 0: src = We1;            break;
    case 1: src = We1 + 128*128;  break;
    case 2: src = We2;            break;
    case 3: src = Wc1;            break;
    case 4: src = Wn1;            break;
    case 5: src = Wn1 + 128*128;  break;
    default: src = Wn2;           break;
  }
  short* dst = wp + m*16384 + (((ft<<2) + ks)*64 + lane)*8;
  int f  = (ft<<4) + (lane & 15);
  int kb = (ks<<5) + ((lane >> 4) << 3);
#pragma unroll
  for (int j = 0; j < 8; ++j)
    dst[j] = (short)f2bf(src[(kb + j)*128 + f]);
}

// ---------- h -> bf16 ----------
__global__ void hconv(const float* __restrict__ h, short* __restrict__ hb)
{
  int i = (blockIdx.x*256 + threadIdx.x) * 8;
  f32x4 a = *(const f32x4*)(h + i);
  f32x4 b = *(const f32x4*)(h + i + 4);
  s16x8 o;
  o[0]=(short)f2bf(a.x); o[1]=(short)f2bf(a.y); o[2]=(short)f2bf(a.z); o[3]=(short)f2bf(a.w);
  o[4]=(short)f2bf(b.x); o[5]=(short)f2bf(b.y); o[6]=(short)f2bf(b.z); o[7]=(short)f2bf(b.w);
  *(s16x8*)(hb + i) = o;
}

// ---------- edge kernel ----------
__global__ __launch_bounds__(256, 2)
void edge_kernel(const short* __restrict__ hb, const float* __restrict__ coord,
                 const int* __restrict__ eidx, const short* __restrict__ wp,
                 const float* __restrict__ be1, const float* __restrict__ be2,
                 const float* __restrict__ bc1, const float* __restrict__ We1,
                 const float* __restrict__ Wc2,
                 float* __restrict__ aggh, float* __restrict__ aggc,
                 float* __restrict__ cntb)
{
  // fragment-order feature tiles: [buf][frag = et*4+ks][lane][8 bf16]
  __shared__ short sA[2][16][64][8];     // 32 KiB; buf0: hrow -> t1, buf1: hcol -> edge_feat
  __shared__ float s_vec[5][128];        // be1, be2, bc1, W1c(=We1 row 256), Wc2
  __shared__ float s_rad[64];
  __shared__ float s_cd[64][3];
  __shared__ int   s_ri[64];
  __shared__ float s_phi[64];

  const int tid  = threadIdx.x;
  const int w    = tid >> 6, lane = tid & 63;
  const int ecol = lane & 15, rgrp = lane >> 4;

  if (tid < 128) {
    s_vec[0][tid] = be1[tid];
    s_vec[1][tid] = be2[tid];
    s_vec[2][tid] = bc1[tid];
    s_vec[3][tid] = We1[256*128 + tid];
    s_vec[4][tid] = Wc2[tid];
  }

  // per-wave weight fragments in VGPRs: wave w owns feature tiles {2w, 2w+1}
  s16x8 wf[4][2][4];                     // [W1a,W1b,W2,Wc1][ft2][ks] = 128 VGPRs
#pragma unroll
  for (int m = 0; m < 4; ++m)
#pragma unroll
    for (int f2 = 0; f2 < 2; ++f2)
#pragma unroll
      for (int ks = 0; ks < 4; ++ks)
        wf[m][f2][ks] = *(const s16x8*)(wp + m*16384 + ((((2*w+f2)<<2) + ks)*64 + lane)*8);

  const int el = tid >> 2, q = tid & 3;       // gather role: 4 threads per edge
  const int fi0 = ((el >> 4) << 2) + q, er = el & 15;

  for (int t = blockIdx.x; t < (EE/64); t += gridDim.x) {
    const int e0 = t << 6;
    if (tid < 64) {
      int e = e0 + tid;
      int r = eidx[e], c = eidx[EE + e];
      s_ri[tid] = r;
      float ax = coord[3*r], ay = coord[3*r+1], az = coord[3*r+2];
      float bx = coord[3*c], by = coord[3*c+1], bz = coord[3*c+2];
      float dx = ax-bx, dy = ay-by, dz = az-bz;
      s_cd[tid][0] = dx; s_cd[tid][1] = dy; s_cd[tid][2] = dz;
      s_rad[tid] = dx*dx + dy*dy + dz*dz;
      s_phi[tid] = 0.f;
    }
    { // gather h rows (bf16) directly into fragment order
      int r = eidx[e0 + el], c = eidx[EE + e0 + el];
      const s16x8* hr = (const s16x8*)(hb + r*128 + q*32);
      const s16x8* hc = (const s16x8*)(hb + c*128 + q*32);
#pragma unroll
      for (int lg = 0; lg < 4; ++lg) {
        *(s16x8*)&sA[0][fi0][lg*16 + er][0] = hr[lg];
        *(s16x8*)&sA[1][fi0][lg*16 + er][0] = hc[lg];
      }
    }
    __syncthreads();                                            // S1

    // GEMM1: D[f][e] = W1a^T hrow^T + W1b^T hcol^T
    f32x4 acc[2][4] = {};
#pragma unroll
    for (int et = 0; et < 4; ++et)
#pragma unroll
      for (int ks = 0; ks < 4; ++ks) {
        s16x8 br = *(const s16x8*)&sA[0][et*4+ks][lane][0];
        s16x8 bc = *(const s16x8*)&sA[1][et*4+ks][lane][0];
        acc[0][et] = mfma16(wf[0][0][ks], br, acc[0][et]);
        acc[1][et] = mfma16(wf[0][1][ks], br, acc[1][et]);
        acc[0][et] = mfma16(wf[1][0][ks], bc, acc[0][et]);
        acc[1][et] = mfma16(wf[1][1][ks], bc, acc[1][et]);
      }
    __syncthreads();                                            // S2 (all reads of sA done)

    // epilogue1: + radial*W1c + be1, SiLU, write t1 frags into sA[0]
#pragma unroll
    for (int f2 = 0; f2 < 2; ++f2) {
      const int ft = 2*w + f2, f0 = ft*16 + rgrp*4;
      const int ks2 = f0 >> 5, lg2 = (f0 & 31) >> 3, j0 = f0 & 7;
      f32x4 w1c = *(const f32x4*)&s_vec[3][f0];
      f32x4 b1  = *(const f32x4*)&s_vec[0][f0];
#pragma unroll
      for (int et = 0; et < 4; ++et) {
        float rad = s_rad[et*16 + ecol];
        f32x4 x = acc[f2][et];
        x.x = silu_f(x.x + rad*w1c.x + b1.x);
        x.y = silu_f(x.y + rad*w1c.y + b1.y);
        x.z = silu_f(x.z + rad*w1c.z + b1.z);
        x.w = silu_f(x.w + rad*w1c.w + b1.w);
        uint2 p; p.x = pack2(x.x, x.y); p.y = pack2(x.z, x.w);
        *(uint2*)&sA[0][et*4 + ks2][lg2*16 + ecol][j0] = p;
      }
    }
    __syncthreads();                                            // S3

    // GEMM2: edge_feat
    f32x4 a2[2][4] = {};
#pragma unroll
    for (int et = 0; et < 4; ++et)
#pragma unroll
      for (int ks = 0; ks < 4; ++ks) {
        s16x8 b = *(const s16x8*)&sA[0][et*4+ks][lane][0];
        a2[0][et] = mfma16(wf[2][0][ks], b, a2[0][et]);
        a2[1][et] = mfma16(wf[2][1][ks], b, a2[1][et]);
      }
    // epilogue2: + be2, SiLU; atomic agg_h; frags into sA[1] (safe: sA[1] last read pre-S2)
#pragma unroll
    for (int f2 = 0; f2 < 2; ++f2) {
      const int ft = 2*w + f2, f0 = ft*16 + rgrp*4;
      const int ks2 = f0 >> 5, lg2 = (f0 & 31) >> 3, j0 = f0 & 7;
      f32x4 b2 = *(const f32x4*)&s_vec[1][f0];
#pragma unroll
      for (int et = 0; et < 4; ++et) {
        f32x4 x = a2[f2][et];
        x.x = silu_f(x.x + b2.x); x.y = silu_f(x.y + b2.y);
        x.z = silu_f(x.z + b2.z); x.w = silu_f(x.w + b2.w);
        int r = s_ri[et*16 + ecol];
        float* ag = aggh + r*128 + f0;
        atomicAdd(ag + 0, x.x); atomicAdd(ag + 1, x.y);
        atomicAdd(ag + 2, x.z); atomicAdd(ag + 3, x.w);
        uint2 p; p.x = pack2(x.x, x.y); p.y = pack2(x.z, x.w);
        *(uint2*)&sA[1][et*4 + ks2][lg2*16 + ecol][j0] = p;
      }
    }
    __syncthreads();                                            // S4

    // GEMM3: phi = silu(ef@Wc1+bc1) @ Wc2
    f32x4 a3[2][4] = {};
#pragma unroll
    for (int et = 0; et < 4; ++et)
#pragma unroll
      for (int ks = 0; ks < 4; ++ks) {
        s16x8 b = *(const s16x8*)&sA[1][et*4+ks][lane][0];
        a3[0][et] = mfma16(wf[3][0][ks], b, a3[0][et]);
        a3[1][et] = mfma16(wf[3][1][ks], b, a3[1][et]);
      }
#pragma unroll
    for (int et = 0; et < 4; ++et) {
      float p = 0.f;
#pragma unroll
      for (int f2 = 0; f2 < 2; ++f2) {
        const int f0 = (2*w+f2)*16 + rgrp*4;
        f32x4 bc = *(const f32x4*)&s_vec[2][f0];
        f32x4 wc = *(const f32x4*)&s_vec[4][f0];
        f32x4 x = a3[f2][et];
        p += silu_f(x.x + bc.x)*wc.x + silu_f(x.y + bc.y)*wc.y
           + silu_f(x.z + bc.z)*wc.z + silu_f(x.w + bc.w)*wc.w;
      }
      p += __shfl_xor(p, 16);
      p += __shfl_xor(p, 32);
      if (rgrp == 0) atomicAdd(&s_phi[et*16 + ecol], p);
    }
    __syncthreads();                                            // S5

    if (tid < 64) {
      int r = s_ri[tid];
      float ph = s_phi[tid];
      atomicAdd(&aggc[3*r+0], s_cd[tid][0]*ph);
      atomicAdd(&aggc[3*r+1], s_cd[tid][1]*ph);
      atomicAdd(&aggc[3*r+2], s_cd[tid][2]*ph);
      atomicAdd(&cntb[r], 1.f);
    }
    __syncthreads();                                            // S6
  }
}

// ---------- node kernel ----------
__global__ __launch_bounds__(256, 2)
void node_kernel(const short* __restrict__ hb, const float* __restrict__ h32,
                 const short* __restrict__ wp, const float* __restrict__ bn1,
                 const float* __restrict__ bn2, float* __restrict__ hout)
{
  __shared__ short sA[2][16][64][8];     // buf0: h -> t, buf1: agg_h
  __shared__ float s_vec[2][128];
  __shared__ float s_out[64][132];       // padded pitch: conflict-free transpose
  const int tid  = threadIdx.x, w = tid >> 6, lane = tid & 63;
  const int ecol = lane & 15, rgrp = lane >> 4;
  if (tid < 128) { s_vec[0][tid] = bn1[tid]; s_vec[1][tid] = bn2[tid]; }

  s16x8 wf[3][2][4];                     // Wn1a, Wn1b, Wn2
#pragma unroll
  for (int m = 0; m < 3; ++m)
#pragma unroll
    for (int f2 = 0; f2 < 2; ++f2)
#pragma unroll
      for (int ks = 0; ks < 4; ++ks)
        wf[m][f2][ks] = *(const s16x8*)(wp + (4+m)*16384 + ((((2*w+f2)<<2) + ks)*64 + lane)*8);

  const int n0 = blockIdx.x << 6;
  const int el = tid >> 2, q = tid & 3;
  const int fi0 = ((el >> 4) << 2) + q, er = el & 15;
  {
    const int node = n0 + el;
    if (node < NN) {
      const s16x8* hr = (const s16x8*)(hb + node*128 + q*32);
      const float* ap = hout + node*128 + q*32;   // agg_h lives in d_out
#pragma unroll
      for (int lg = 0; lg < 4; ++lg) {
        *(s16x8*)&sA[0][fi0][lg*16 + er][0] = hr[lg];
        f32x4 u = *(const f32x4*)(ap + lg*8);
        f32x4 v = *(const f32x4*)(ap + lg*8 + 4);
        s16x8 o;
        o[0]=(short)f2bf(u.x); o[1]=(short)f2bf(u.y); o[2]=(short)f2bf(u.z); o[3]=(short)f2bf(u.w);
        o[4]=(short)f2bf(v.x); o[5]=(short)f2bf(v.y); o[6]=(short)f2bf(v.z); o[7]=(short)f2bf(v.w);
        *(s16x8*)&sA[1][fi0][lg*16 + er][0] = o;
      }
    } else {
      s16x8 z = {};
#pragma unroll
      for (int lg = 0; lg < 4; ++lg) {
        *(s16x8*)&sA[0][fi0][lg*16 + er][0] = z;
        *(s16x8*)&sA[1][fi0][lg*16 + er][0] = z;
      }
    }
  }
  __syncthreads();

  f32x4 acc[2][4] = {};
#pragma unroll
  for (int et = 0; et < 4; ++et)
#pragma unroll
    for (int ks = 0; ks < 4; ++ks) {
      s16x8 bh = *(const s16x8*)&sA[0][et*4+ks][lane][0];
      s16x8 ba = *(const s16x8*)&sA[1][et*4+ks][lane][0];
      acc[0][et] = mfma16(wf[0][0][ks], bh, acc[0][et]);
      acc[1][et] = mfma16(wf[0][1][ks], bh, acc[1][et]);
      acc[0][et] = mfma16(wf[1][0][ks], ba, acc[0][et]);
      acc[1][et] = mfma16(wf[1][1][ks], ba, acc[1][et]);
    }
  __syncthreads();
#pragma unroll
  for (int f2 = 0; f2 < 2; ++f2) {
    const int ft = 2*w + f2, f0 = ft*16 + rgrp*4;
    const int ks2 = f0 >> 5, lg2 = (f0 & 31) >> 3, j0 = f0 & 7;
    f32x4 b1 = *(const f32x4*)&s_vec[0][f0];
#pragma unroll
    for (int et = 0; et < 4; ++et) {
      f32x4 x = acc[f2][et];
      x.x = silu_f(x.x + b1.x); x.y = silu_f(x.y + b1.y);
      x.z = silu_f(x.z + b1.z); x.w = silu_f(x.w + b1.w);
      uint2 p; p.x = pack2(x.x, x.y); p.y = pack2(x.z, x.w);
      *(uint2*)&sA[0][et*4 + ks2][lg2*16 + ecol][j0] = p;
    }
  }
  __syncthreads();

  f32x4 a2[2][4] = {};
#pragma unroll
  for (int et = 0; et < 4; ++et)
#pragma unroll
    for (int ks = 0; ks < 4; ++ks) {
      s16x8 b = *(const s16x8*)&sA[0][et*4+ks][lane][0];
      a2[0][et] = mfma16(wf[2][0][ks], b, a2[0][et]);
      a2[1][et] = mfma16(wf[2][1][ks], b, a2[1][et]);
    }
#pragma unroll
  for (int f2 = 0; f2 < 2; ++f2) {
    const int f0 = (2*w+f2)*16 + rgrp*4;
    f32x4 b2 = *(const f32x4*)&s_vec[1][f0];
#pragma unroll
    for (int et = 0; et < 4; ++et) {
      f32x4 x = a2[f2][et];
      x.x += b2.x; x.y += b2.y; x.z += b2.z; x.w += b2.w;
      *(f32x4*)&s_out[et*16 + ecol][f0] = x;
    }
  }
  __syncthreads();
  {
    const int node = n0 + el;
    if (node < NN) {
#pragma unroll
      for (int i = 0; i < 8; ++i) {
        f32x4 o  = *(const f32x4*)&s_out[el][q*32 + i*4];
        f32x4 hv = *(const f32x4*)(h32 + node*128 + q*32 + i*4);
        o.x += hv.x; o.y += hv.y; o.z += hv.z; o.w += hv.w;
        *(f32x4*)(hout + node*128 + q*32 + i*4) = o;
      }
    }
  }
}

// ---------- coord kernel ----------
__global__ void coord_kernel(const float* __restrict__ coord, const float* __restrict__ aggc,
                             const float* __restrict__ cntb, float* __restrict__ out)
{
  int i = blockIdx.x*256 + threadIdx.x;
  if (i < NN) {
    float inv = 1.f / fmaxf(cntb[i], 1.f);
    out[NHF + 3*i+0] = coord[3*i+0] + aggc[3*i+0]*inv;
    out[NHF + 3*i+1] = coord[3*i+1] + aggc[3*i+1]*inv;
    out[NHF + 3*i+2] = coord[3*i+2] + aggc[3*i+2]*inv;
  }
}

extern "C" void kernel_launch(void* const* d_in, const int* in_sizes, int n_in,
                              void* d_out, int out_size, void* d_ws, size_t ws_size,
                              hipStream_t stream)
{
  (void)in_sizes; (void)n_in; (void)out_size; (void)ws_size;
  const float* h    = (const float*)d_in[0];
  const float* crd  = (const float*)d_in[1];
  const int*   eidx = (const int*)  d_in[2];
  const float* We1  = (const float*)d_in[3];
  const float* be1  = (const float*)d_in[4];
  const float* We2  = (const float*)d_in[5];
  const float* be2  = (const float*)d_in[6];
  const float* Wn1  = (const float*)d_in[7];
  const float* bn1  = (const float*)d_in[8];
  const float* Wn2  = (const float*)d_in[9];
  const float* bn2  = (const float*)d_in[10];
  const float* Wc1  = (const float*)d_in[11];
  const float* bc1  = (const float*)d_in[12];
  const float* Wc2  = (const float*)d_in[13];
  float* out = (float*)d_out;
  char*  ws  = (char*)d_ws;

  short* hb   = (short*)ws;                    // 12,800,000 B: h in bf16
  short* wp   = (short*)(ws + 12800000);       //    229,376 B: packed weights
  float* aggc = (float*)(ws + 13029376);       //    600,000 B
  float* cntb = (float*)(ws + 13629376);       //    200,000 B

  // zero accumulators every call (harness does not re-poison between replays)
  hipMemsetAsync(out, 0, (size_t)NHF*4, stream);          // agg_h region of d_out
  hipMemsetAsync(ws + 13029376, 0, 800000, stream);       // agg_c + cnt

  pack_weights<<<dim3(224), dim3(64), 0, stream>>>(We1, We2, Wc1, Wn1, Wn2, wp);
  hconv<<<dim3(3125), dim3(256), 0, stream>>>(h, hb);
  edge_kernel<<<dim3(2048), dim3(256), 0, stream>>>(hb, crd, eidx, wp, be1, be2, bc1,
                                                    We1, Wc2, out, aggc, cntb);
  node_kernel<<<dim3(782), dim3(256), 0, stream>>>(hb, h, wp, bn1, bn2, out);
  coord_kernel<<<dim3(196), dim3(256), 0, stream>>>(crd, aggc, cntb, out);
}

// Round 2
// 998.819 us; speedup vs baseline: 3.0028x; 3.0028x over previous
//
#include <hip/hip_runtime.h>

// EGNN E_GCL fused kernels for MI355X (gfx950), bf16 MFMA path.
// Round 2: counting-sort edges by row (hist/scan/scatter -> perm), then
// segmented-suffix-sum dedup of aggregation atomics inside the edge kernel.
// Round-1 evidence: 205M f32 atomics -> 3.4 GB HBM writes, 69 G atomics/s,
// atomic-throughput-bound (MfmaUtil 2.8%, HBM 16%).

typedef float f32x4 __attribute__((ext_vector_type(4)));
typedef short s16x8 __attribute__((ext_vector_type(8)));

#define NN   50000
#define EE   1600000
#define NHF  6400000   // N*128
#define NBIN 50000

__device__ __forceinline__ unsigned short f2bf(float x){
  union { float f; unsigned int u; } v; v.f = x;
  unsigned int r = v.u + 0x7fffu + ((v.u >> 16) & 1u);
  return (unsigned short)(r >> 16);
}
__device__ __forceinline__ unsigned int pack2(float a, float b){
  return (unsigned int)f2bf(a) | ((unsigned int)f2bf(b) << 16);
}
__device__ __forceinline__ float silu_f(float x){ return x / (1.f + __expf(-x)); }

__device__ __forceinline__ f32x4 mfma16(s16x8 a, s16x8 b, f32x4 c){
  return __builtin_amdgcn_mfma_f32_16x16x32_bf16(a, b, c, 0, 0, 0);
}

// ---------- weight pack: A-fragments of W^T ----------
__global__ void pack_weights(const float* __restrict__ We1, const float* __restrict__ We2,
                             const float* __restrict__ Wc1, const float* __restrict__ Wn1,
                             const float* __restrict__ Wn2, short* __restrict__ wp)
{
  int b = blockIdx.x;              // 7*32 blocks, 64 threads
  int m = b >> 5, t = b & 31;
  int ft = t >> 2, ks = t & 3;
  int lane = threadIdx.x;
  const float* src;
  switch (m) {
    case 0: src = We1;            break;
    case 1: src = We1 + 128*128;  break;
    case 2: src = We2;            break;
    case 3: src = Wc1;            break;
    case 4: src = Wn1;            break;
    case 5: src = Wn1 + 128*128;  break;
    default: src = Wn2;           break;
  }
  short* dst = wp + m*16384 + (((ft<<2) + ks)*64 + lane)*8;
  int f  = (ft<<4) + (lane & 15);
  int kb = (ks<<5) + ((lane >> 4) << 3);
#pragma unroll
  for (int j = 0; j < 8; ++j)
    dst[j] = (short)f2bf(src[(kb + j)*128 + f]);
}

// ---------- h -> bf16 ----------
__global__ void hconv(const float* __restrict__ h, short* __restrict__ hb)
{
  int i = (blockIdx.x*256 + threadIdx.x) * 8;
  f32x4 a = *(const f32x4*)(h + i);
  f32x4 b = *(const f32x4*)(h + i + 4);
  s16x8 o;
  o[0]=(short)f2bf(a.x); o[1]=(short)f2bf(a.y); o[2]=(short)f2bf(a.z); o[3]=(short)f2bf(a.w);
  o[4]=(short)f2bf(b.x); o[5]=(short)f2bf(b.y); o[6]=(short)f2bf(b.z); o[7]=(short)f2bf(b.w);
  *(s16x8*)(hb + i) = o;
}

// ---------- counting sort by row: hist -> scan -> scatter ----------
__global__ void hist_k(const int* __restrict__ eidx, int* __restrict__ hist)
{
  int e = blockIdx.x*256 + threadIdx.x;
  if (e < EE) atomicAdd(&hist[eidx[e]], 1);
}

__global__ void scan_k(const int* __restrict__ hist, int* __restrict__ cur)
{
  // 1 block x 256 threads; chunk of 196 bins per thread
  __shared__ int s_a[256];
  const int t = threadIdx.x;
  const int lo = t * 196;
  const int hi = (lo + 196 < NBIN) ? lo + 196 : NBIN;
  int s = 0;
  for (int i = lo; i < hi; ++i) s += hist[i];
  s_a[t] = s;
  __syncthreads();
  int acc = s;
#pragma unroll
  for (int d = 1; d < 256; d <<= 1) {
    int u = (t >= d) ? s_a[t - d] : 0;
    __syncthreads();
    acc += u;
    s_a[t] = acc;
    __syncthreads();
  }
  int run = acc - s;          // exclusive prefix of this thread's chunk
  for (int i = lo; i < hi; ++i) { cur[i] = run; run += hist[i]; }
}

__global__ void scatter_k(const int* __restrict__ eidx, int* __restrict__ cur,
                          int* __restrict__ perm)
{
  int e = blockIdx.x*256 + threadIdx.x;
  if (e < EE) {
    int p = atomicAdd(&cur[eidx[e]], 1);
    perm[p] = e;
  }
}

// ---------- edge kernel ----------
__global__ __launch_bounds__(256, 2)
void edge_kernel(const short* __restrict__ hb, const float* __restrict__ coord,
                 const int* __restrict__ eidx, const int* __restrict__ perm,
                 const short* __restrict__ wp,
                 const float* __restrict__ be1, const float* __restrict__ be2,
                 const float* __restrict__ bc1, const float* __restrict__ We1,
                 const float* __restrict__ Wc2,
                 float* __restrict__ aggh, float* __restrict__ aggc,
                 float* __restrict__ cntb)
{
  __shared__ short sA[2][16][64][8];     // 32 KiB
  __shared__ float s_vec[5][128];        // be1, be2, bc1, W1c, Wc2
  __shared__ float s_rad[64];
  __shared__ float s_cd[64][3];
  __shared__ int   s_ri[64];
  __shared__ float s_phi[64];

  const int tid  = threadIdx.x;
  const int w    = tid >> 6, lane = tid & 63;
  const int ecol = lane & 15, rgrp = lane >> 4;

  if (tid < 128) {
    s_vec[0][tid] = be1[tid];
    s_vec[1][tid] = be2[tid];
    s_vec[2][tid] = bc1[tid];
    s_vec[3][tid] = We1[256*128 + tid];
    s_vec[4][tid] = Wc2[tid];
  }

  s16x8 wf[4][2][4];                     // W1a,W1b,W2,Wc1 fragments (128 VGPRs)
#pragma unroll
  for (int m = 0; m < 4; ++m)
#pragma unroll
    for (int f2 = 0; f2 < 2; ++f2)
#pragma unroll
      for (int ks = 0; ks < 4; ++ks)
        wf[m][f2][ks] = *(const s16x8*)(wp + m*16384 + ((((2*w+f2)<<2) + ks)*64 + lane)*8);

  const int el = tid >> 2, q = tid & 3;       // gather role: 4 threads per edge
  const int fi0 = ((el >> 4) << 2) + q, er = el & 15;

  for (int t = blockIdx.x; t < (EE/64); t += gridDim.x) {
    const int e0 = t << 6;
    if (tid < 64) {
      int e = perm[e0 + tid];
      int r = eidx[e], c = eidx[EE + e];
      s_ri[tid] = r;
      float ax = coord[3*r], ay = coord[3*r+1], az = coord[3*r+2];
      float bx = coord[3*c], by = coord[3*c+1], bz = coord[3*c+2];
      float dx = ax-bx, dy = ay-by, dz = az-bz;
      s_cd[tid][0] = dx; s_cd[tid][1] = dy; s_cd[tid][2] = dz;
      s_rad[tid] = dx*dx + dy*dy + dz*dz;
      s_phi[tid] = 0.f;
    }
    { // gather h rows (bf16) directly into fragment order
      int e = perm[e0 + el];
      int r = eidx[e], c = eidx[EE + e];
      const s16x8* hr = (const s16x8*)(hb + r*128 + q*32);
      const s16x8* hc = (const s16x8*)(hb + c*128 + q*32);
#pragma unroll
      for (int lg = 0; lg < 4; ++lg) {
        *(s16x8*)&sA[0][fi0][lg*16 + er][0] = hr[lg];
        *(s16x8*)&sA[1][fi0][lg*16 + er][0] = hc[lg];
      }
    }
    __syncthreads();                                            // S1

    // GEMM1
    f32x4 acc[2][4] = {};
#pragma unroll
    for (int et = 0; et < 4; ++et)
#pragma unroll
      for (int ks = 0; ks < 4; ++ks) {
        s16x8 br = *(const s16x8*)&sA[0][et*4+ks][lane][0];
        s16x8 bc = *(const s16x8*)&sA[1][et*4+ks][lane][0];
        acc[0][et] = mfma16(wf[0][0][ks], br, acc[0][et]);
        acc[1][et] = mfma16(wf[0][1][ks], br, acc[1][et]);
        acc[0][et] = mfma16(wf[1][0][ks], bc, acc[0][et]);
        acc[1][et] = mfma16(wf[1][1][ks], bc, acc[1][et]);
      }
    __syncthreads();                                            // S2

    // epilogue1: + radial*W1c + be1, SiLU -> t1 frags into sA[0]
#pragma unroll
    for (int f2 = 0; f2 < 2; ++f2) {
      const int ft = 2*w + f2, f0 = ft*16 + rgrp*4;
      const int ks2 = f0 >> 5, lg2 = (f0 & 31) >> 3, j0 = f0 & 7;
      f32x4 w1c = *(const f32x4*)&s_vec[3][f0];
      f32x4 b1  = *(const f32x4*)&s_vec[0][f0];
#pragma unroll
      for (int et = 0; et < 4; ++et) {
        float rad = s_rad[et*16 + ecol];
        f32x4 x = acc[f2][et];
        x.x = silu_f(x.x + rad*w1c.x + b1.x);
        x.y = silu_f(x.y + rad*w1c.y + b1.y);
        x.z = silu_f(x.z + rad*w1c.z + b1.z);
        x.w = silu_f(x.w + rad*w1c.w + b1.w);
        uint2 p; p.x = pack2(x.x, x.y); p.y = pack2(x.z, x.w);
        *(uint2*)&sA[0][et*4 + ks2][lg2*16 + ecol][j0] = p;
      }
    }
    __syncthreads();                                            // S3

    // GEMM2: edge_feat
    f32x4 a2[2][4] = {};
#pragma unroll
    for (int et = 0; et < 4; ++et)
#pragma unroll
      for (int ks = 0; ks < 4; ++ks) {
        s16x8 b = *(const s16x8*)&sA[0][et*4+ks][lane][0];
        a2[0][et] = mfma16(wf[2][0][ks], b, a2[0][et]);
        a2[1][et] = mfma16(wf[2][1][ks], b, a2[1][et]);
      }
    // epilogue2: + be2, SiLU; frags into sA[1]; seg-reduced atomics into agg_h.
    // Rows are sorted within the tile (perm), so equal rows are contiguous:
    // segmented suffix-sum across the 16-lane edge group, heads do the atomic.
#pragma unroll
    for (int et = 0; et < 4; ++et) {
      const int r_l = s_ri[et*16 + ecol];
      const bool head = (ecol == 0) || (s_ri[et*16 + ecol - 1] != r_l);
      f32x4 xx0, xx1;
#pragma unroll
      for (int f2 = 0; f2 < 2; ++f2) {
        const int ft = 2*w + f2, f0 = ft*16 + rgrp*4;
        const int ks2 = f0 >> 5, lg2 = (f0 & 31) >> 3, j0 = f0 & 7;
        f32x4 b2 = *(const f32x4*)&s_vec[1][f0];
        f32x4 x = a2[f2][et];
        x.x = silu_f(x.x + b2.x); x.y = silu_f(x.y + b2.y);
        x.z = silu_f(x.z + b2.z); x.w = silu_f(x.w + b2.w);
        uint2 p; p.x = pack2(x.x, x.y); p.y = pack2(x.z, x.w);
        *(uint2*)&sA[1][et*4 + ks2][lg2*16 + ecol][j0] = p;
        if (f2 == 0) xx0 = x; else xx1 = x;
      }
#pragma unroll
      for (int d = 1; d < 16; d <<= 1) {
        const int sl = lane + d;
        int  r2 = __shfl(r_l, sl, 64);
        bool ok = ((ecol + d) < 16) && (r2 == r_l);
        float u0x = __shfl(xx0.x, sl, 64), u0y = __shfl(xx0.y, sl, 64);
        float u0z = __shfl(xx0.z, sl, 64), u0w = __shfl(xx0.w, sl, 64);
        float u1x = __shfl(xx1.x, sl, 64), u1y = __shfl(xx1.y, sl, 64);
        float u1z = __shfl(xx1.z, sl, 64), u1w = __shfl(xx1.w, sl, 64);
        if (ok) {
          xx0.x+=u0x; xx0.y+=u0y; xx0.z+=u0z; xx0.w+=u0w;
          xx1.x+=u1x; xx1.y+=u1y; xx1.z+=u1z; xx1.w+=u1w;
        }
      }
      if (head) {
        const int f0a = (2*w+0)*16 + rgrp*4;
        const int f0b = (2*w+1)*16 + rgrp*4;
        float* aga = aggh + (size_t)r_l*128 + f0a;
        float* agb = aggh + (size_t)r_l*128 + f0b;
        atomicAdd(aga+0, xx0.x); atomicAdd(aga+1, xx0.y);
        atomicAdd(aga+2, xx0.z); atomicAdd(aga+3, xx0.w);
        atomicAdd(agb+0, xx1.x); atomicAdd(agb+1, xx1.y);
        atomicAdd(agb+2, xx1.z); atomicAdd(agb+3, xx1.w);
      }
    }
    __syncthreads();                                            // S4

    // GEMM3: phi = silu(ef@Wc1+bc1) @ Wc2
    f32x4 a3[2][4] = {};
#pragma unroll
    for (int et = 0; et < 4; ++et)
#pragma unroll
      for (int ks = 0; ks < 4; ++ks) {
        s16x8 b = *(const s16x8*)&sA[1][et*4+ks][lane][0];
        a3[0][et] = mfma16(wf[3][0][ks], b, a3[0][et]);
        a3[1][et] = mfma16(wf[3][1][ks], b, a3[1][et]);
      }
#pragma unroll
    for (int et = 0; et < 4; ++et) {
      float p = 0.f;
#pragma unroll
      for (int f2 = 0; f2 < 2; ++f2) {
        const int f0 = (2*w+f2)*16 + rgrp*4;
        f32x4 bc = *(const f32x4*)&s_vec[2][f0];
        f32x4 wc = *(const f32x4*)&s_vec[4][f0];
        f32x4 x = a3[f2][et];
        p += silu_f(x.x + bc.x)*wc.x + silu_f(x.y + bc.y)*wc.y
           + silu_f(x.z + bc.z)*wc.z + silu_f(x.w + bc.w)*wc.w;
      }
      p += __shfl_xor(p, 16);
      p += __shfl_xor(p, 32);
      if (rgrp == 0) atomicAdd(&s_phi[et*16 + ecol], p);
    }
    __syncthreads();                                            // S5

    // coord aggregation: segmented suffix-sum over the 64 sorted rows
    if (tid < 64) {
      int r = s_ri[tid];
      float ph = s_phi[tid];
      float cx = s_cd[tid][0]*ph, cy = s_cd[tid][1]*ph, cz = s_cd[tid][2]*ph, c1 = 1.f;
#pragma unroll
      for (int d = 1; d < 64; d <<= 1) {
        const int sl = tid + d;
        int   r2 = __shfl(r,  sl, 64);
        float ux = __shfl(cx, sl, 64), uy = __shfl(cy, sl, 64);
        float uz = __shfl(cz, sl, 64), uw = __shfl(c1, sl, 64);
        if ((sl < 64) && (r2 == r)) { cx+=ux; cy+=uy; cz+=uz; c1+=uw; }
      }
      if (tid == 0 || s_ri[tid-1] != r) {
        atomicAdd(&aggc[3*r+0], cx); atomicAdd(&aggc[3*r+1], cy);
        atomicAdd(&aggc[3*r+2], cz); atomicAdd(&cntb[r], c1);
      }
    }
    __syncthreads();                                            // S6
  }
}

// ---------- node kernel ----------
__global__ __launch_bounds__(256, 2)
void node_kernel(const short* __restrict__ hb, const float* __restrict__ h32,
                 const short* __restrict__ wp, const float* __restrict__ bn1,
                 const float* __restrict__ bn2, float* __restrict__ hout)
{
  __shared__ short sA[2][16][64][8];
  __shared__ float s_vec[2][128];
  __shared__ float s_out[64][132];
  const int tid  = threadIdx.x, w = tid >> 6, lane = tid & 63;
  const int ecol = lane & 15, rgrp = lane >> 4;
  if (tid < 128) { s_vec[0][tid] = bn1[tid]; s_vec[1][tid] = bn2[tid]; }

  s16x8 wf[3][2][4];
#pragma unroll
  for (int m = 0; m < 3; ++m)
#pragma unroll
    for (int f2 = 0; f2 < 2; ++f2)
#pragma unroll
      for (int ks = 0; ks < 4; ++ks)
        wf[m][f2][ks] = *(const s16x8*)(wp + (4+m)*16384 + ((((2*w+f2)<<2) + ks)*64 + lane)*8);

  const int n0 = blockIdx.x << 6;
  const int el = tid >> 2, q = tid & 3;
  const int fi0 = ((el >> 4) << 2) + q, er = el & 15;
  {
    const int node = n0 + el;
    if (node < NN) {
      const s16x8* hr = (const s16x8*)(hb + node*128 + q*32);
      const float* ap = hout + node*128 + q*32;   // agg_h lives in d_out
#pragma unroll
      for (int lg = 0; lg < 4; ++lg) {
        *(s16x8*)&sA[0][fi0][lg*16 + er][0] = hr[lg];
        f32x4 u = *(const f32x4*)(ap + lg*8);
        f32x4 v = *(const f32x4*)(ap + lg*8 + 4);
        s16x8 o;
        o[0]=(short)f2bf(u.x); o[1]=(short)f2bf(u.y); o[2]=(short)f2bf(u.z); o[3]=(short)f2bf(u.w);
        o[4]=(short)f2bf(v.x); o[5]=(short)f2bf(v.y); o[6]=(short)f2bf(v.z); o[7]=(short)f2bf(v.w);
        *(s16x8*)&sA[1][fi0][lg*16 + er][0] = o;
      }
    } else {
      s16x8 z = {};
#pragma unroll
      for (int lg = 0; lg < 4; ++lg) {
        *(s16x8*)&sA[0][fi0][lg*16 + er][0] = z;
        *(s16x8*)&sA[1][fi0][lg*16 + er][0] = z;
      }
    }
  }
  __syncthreads();

  f32x4 acc[2][4] = {};
#pragma unroll
  for (int et = 0; et < 4; ++et)
#pragma unroll
    for (int ks = 0; ks < 4; ++ks) {
      s16x8 bh = *(const s16x8*)&sA[0][et*4+ks][lane][0];
      s16x8 ba = *(const s16x8*)&sA[1][et*4+ks][lane][0];
      acc[0][et] = mfma16(wf[0][0][ks], bh, acc[0][et]);
      acc[1][et] = mfma16(wf[0][1][ks], bh, acc[1][et]);
      acc[0][et] = mfma16(wf[1][0][ks], ba, acc[0][et]);
      acc[1][et] = mfma16(wf[1][1][ks], ba, acc[1][et]);
    }
  __syncthreads();
#pragma unroll
  for (int f2 = 0; f2 < 2; ++f2) {
    const int ft = 2*w + f2, f0 = ft*16 + rgrp*4;
    const int ks2 = f0 >> 5, lg2 = (f0 & 31) >> 3, j0 = f0 & 7;
    f32x4 b1 = *(const f32x4*)&s_vec[0][f0];
#pragma unroll
    for (int et = 0; et < 4; ++et) {
      f32x4 x = acc[f2][et];
      x.x = silu_f(x.x + b1.x); x.y = silu_f(x.y + b1.y);
      x.z = silu_f(x.z + b1.z); x.w = silu_f(x.w + b1.w);
      uint2 p; p.x = pack2(x.x, x.y); p.y = pack2(x.z, x.w);
      *(uint2*)&sA[0][et*4 + ks2][lg2*16 + ecol][j0] = p;
    }
  }
  __syncthreads();

  f32x4 a2[2][4] = {};
#pragma unroll
  for (int et = 0; et < 4; ++et)
#pragma unroll
    for (int ks = 0; ks < 4; ++ks) {
      s16x8 b = *(const s16x8*)&sA[0][et*4+ks][lane][0];
      a2[0][et] = mfma16(wf[2][0][ks], b, a2[0][et]);
      a2[1][et] = mfma16(wf[2][1][ks], b, a2[1][et]);
    }
#pragma unroll
  for (int f2 = 0; f2 < 2; ++f2) {
    const int f0 = (2*w+f2)*16 + rgrp*4;
    f32x4 b2 = *(const f32x4*)&s_vec[1][f0];
#pragma unroll
    for (int et = 0; et < 4; ++et) {
      f32x4 x = a2[f2][et];
      x.x += b2.x; x.y += b2.y; x.z += b2.z; x.w += b2.w;
      *(f32x4*)&s_out[et*16 + ecol][f0] = x;
    }
  }
  __syncthreads();
  {
    const int node = n0 + el;
    if (node < NN) {
#pragma unroll
      for (int i = 0; i < 8; ++i) {
        f32x4 o  = *(const f32x4*)&s_out[el][q*32 + i*4];
        f32x4 hv = *(const f32x4*)(h32 + node*128 + q*32 + i*4);
        o.x += hv.x; o.y += hv.y; o.z += hv.z; o.w += hv.w;
        *(f32x4*)(hout + node*128 + q*32 + i*4) = o;
      }
    }
  }
}

// ---------- coord kernel ----------
__global__ void coord_kernel(const float* __restrict__ coord, const float* __restrict__ aggc,
                             const float* __restrict__ cntb, float* __restrict__ out)
{
  int i = blockIdx.x*256 + threadIdx.x;
  if (i < NN) {
    float inv = 1.f / fmaxf(cntb[i], 1.f);
    out[NHF + 3*i+0] = coord[3*i+0] + aggc[3*i+0]*inv;
    out[NHF + 3*i+1] = coord[3*i+1] + aggc[3*i+1]*inv;
    out[NHF + 3*i+2] = coord[3*i+2] + aggc[3*i+2]*inv;
  }
}

extern "C" void kernel_launch(void* const* d_in, const int* in_sizes, int n_in,
                              void* d_out, int out_size, void* d_ws, size_t ws_size,
                              hipStream_t stream)
{
  (void)in_sizes; (void)n_in; (void)out_size; (void)ws_size;
  const float* h    = (const float*)d_in[0];
  const float* crd  = (const float*)d_in[1];
  const int*   eidx = (const int*)  d_in[2];
  const float* We1  = (const float*)d_in[3];
  const float* be1  = (const float*)d_in[4];
  const float* We2  = (const float*)d_in[5];
  const float* be2  = (const float*)d_in[6];
  const float* Wn1  = (const float*)d_in[7];
  const float* bn1  = (const float*)d_in[8];
  const float* Wn2  = (const float*)d_in[9];
  const float* bn2  = (const float*)d_in[10];
  const float* Wc1  = (const float*)d_in[11];
  const float* bc1  = (const float*)d_in[12];
  const float* Wc2  = (const float*)d_in[13];
  float* out = (float*)d_out;
  char*  ws  = (char*)d_ws;

  short* hb   = (short*)ws;                    // 12,800,000 B
  short* wp   = (short*)(ws + 12800000);       //    229,376 B
  float* aggc = (float*)(ws + 13029376);       //    600,000 B
  float* cntb = (float*)(ws + 13629376);       //    200,000 B
  int*   hist = (int*)  (ws + 13829376);       //    200,000 B
  int*   cur  = (int*)  (ws + 14029376);       //    200,000 B
  int*   perm = (int*)  (ws + 14229376);       //  6,400,000 B  (end: 20,629,376)

  // zero accumulators every call (harness does not re-poison between replays)
  hipMemsetAsync(out, 0, (size_t)NHF*4, stream);          // agg_h region of d_out
  hipMemsetAsync(ws + 13029376, 0, 800000, stream);       // agg_c + cnt
  hipMemsetAsync(ws + 13829376, 0, 200000, stream);       // hist

  pack_weights<<<dim3(224), dim3(64), 0, stream>>>(We1, We2, Wc1, Wn1, Wn2, wp);
  hconv<<<dim3(3125), dim3(256), 0, stream>>>(h, hb);
  hist_k<<<dim3(6250), dim3(256), 0, stream>>>(eidx, hist);
  scan_k<<<dim3(1), dim3(256), 0, stream>>>(hist, cur);
  scatter_k<<<dim3(6250), dim3(256), 0, stream>>>(eidx, cur, perm);
  edge_kernel<<<dim3(2048), dim3(256), 0, stream>>>(hb, crd, eidx, perm, wp,
                                                    be1, be2, bc1, We1, Wc2,
                                                    out, aggc, cntb);
  node_kernel<<<dim3(782), dim3(256), 0, stream>>>(hb, h, wp, bn1, bn2, out);
  coord_kernel<<<dim3(196), dim3(256), 0, stream>>>(crd, aggc, cntb, out);
}